// Round 1
// baseline (4722.935 us; speedup 1.0000x reference)
//
#include <hip/hip_runtime.h>
#include <hip/hip_bf16.h>
#include <math.h>

// Problem constants
#define N_TRAIN 4096
#define N_FEAT  64
#define NHID    256
#define ENC     256
#define GH      256
#define AH      64
#define NANTES  32768
#define TSTEPS  32

__device__ __forceinline__ float sigmoidf_(float x) {
    return 1.0f / (1.0f + __expf(-x));
}

// ---------------------------------------------------------------------------
// Kernel 0: zero the e-sum accumulator (32 x 256 floats)
// ---------------------------------------------------------------------------
__global__ void zero_kernel(float* __restrict__ esum) {
    int tid = blockIdx.x * blockDim.x + threadIdx.x;
    for (int i = tid; i < TSTEPS * GH; i += gridDim.x * blockDim.x)
        esum[i] = 0.0f;
}

// ---------------------------------------------------------------------------
// Kernel A: fused encoder -> x_proj -> 32-step LSTM -> per-step h column sums
// Grid: 256 blocks x 512 threads. Block b owns rows [b*16, b*16+16).
// Thread (j = tid&255, rh = tid>>8) owns hidden column j for 8 rows
// (rows rh*8 .. rh*8+7 of the block's 16).
// ---------------------------------------------------------------------------
__global__ __launch_bounds__(512, 2) void lstm_kernel(
    const float* __restrict__ ctx,
    const float* __restrict__ encW1, const float* __restrict__ encb1,
    const float* __restrict__ encW2, const float* __restrict__ encb2,
    const float* __restrict__ Wih,  const float* __restrict__ Whh,
    const float* __restrict__ bih,  const float* __restrict__ bhh,
    float* __restrict__ esum)
{
    __shared__ float ctx_lds[16 * N_FEAT];   // 4 KB
    __shared__ float buf[16 * 256];          // 16 KB: hid -> phi -> h per step

    const int tid   = threadIdx.x;
    const int j     = tid & 255;
    const int rh    = tid >> 8;       // 0 or 1
    const int rbase = rh * 8;
    const int r0    = blockIdx.x * 16;

    // ---- stage context rows ----
    for (int t = tid; t < 16 * N_FEAT; t += 512)
        ctx_lds[t] = ctx[r0 * N_FEAT + t];
    __syncthreads();

    // ---- hid = relu(ctx @ encW1 + b1) ----
    {
        float acc[8];
        float b = encb1[j];
        #pragma unroll
        for (int r = 0; r < 8; ++r) acc[r] = b;
        for (int k = 0; k < N_FEAT; ++k) {
            float w = encW1[k * NHID + j];
            #pragma unroll
            for (int r = 0; r < 8; ++r)
                acc[r] = fmaf(ctx_lds[(rbase + r) * N_FEAT + k], w, acc[r]);
        }
        #pragma unroll
        for (int r = 0; r < 8; ++r)
            buf[(rbase + r) * 256 + j] = fmaxf(acc[r], 0.0f);
    }
    __syncthreads();

    // ---- phi = hid @ encW2 + b2 ----
    {
        float p[8];
        float b = encb2[j];
        #pragma unroll
        for (int r = 0; r < 8; ++r) p[r] = b;
        for (int k = 0; k < NHID; ++k) {
            float w = encW2[k * ENC + j];
            #pragma unroll
            for (int r = 0; r < 8; ++r)
                p[r] = fmaf(buf[(rbase + r) * 256 + k], w, p[r]);
        }
        __syncthreads();   // all reads of hid done
        #pragma unroll
        for (int r = 0; r < 8; ++r)
            buf[(rbase + r) * 256 + j] = p[r];
    }
    __syncthreads();

    // ---- x_proj[g][r] for gate column m = g*256 + j ----
    float xp[4][8];
    #pragma unroll
    for (int g = 0; g < 4; ++g) {
        int m = g * 256 + j;
        float b = bih[m] + bhh[m];
        #pragma unroll
        for (int r = 0; r < 8; ++r) xp[g][r] = b;
        const float4* wrow = (const float4*)(Wih + m * ENC);
        for (int k4 = 0; k4 < ENC / 4; ++k4) {
            float4 w = wrow[k4];
            #pragma unroll
            for (int r = 0; r < 8; ++r) {
                const float* ph = &buf[(rbase + r) * 256 + k4 * 4];
                float v = xp[g][r];
                v = fmaf(ph[0], w.x, v);
                v = fmaf(ph[1], w.y, v);
                v = fmaf(ph[2], w.z, v);
                v = fmaf(ph[3], w.w, v);
                xp[g][r] = v;
            }
        }
    }
    __syncthreads();

    // ---- LSTM over 32 steps ----
    float h[8], c[8];
    #pragma unroll
    for (int r = 0; r < 8; ++r) { h[r] = 0.0f; c[r] = 0.0f; }

    const float4* w0 = (const float4*)(Whh + (0 * 256 + j) * 256);
    const float4* w1 = (const float4*)(Whh + (1 * 256 + j) * 256);
    const float4* w2 = (const float4*)(Whh + (2 * 256 + j) * 256);
    const float4* w3 = (const float4*)(Whh + (3 * 256 + j) * 256);

    for (int t = 0; t < TSTEPS; ++t) {
        // publish h into LDS
        #pragma unroll
        for (int r = 0; r < 8; ++r)
            buf[(rbase + r) * 256 + j] = h[r];
        __syncthreads();

        float ga[4][8];
        #pragma unroll
        for (int g = 0; g < 4; ++g)
            #pragma unroll
            for (int r = 0; r < 8; ++r) ga[g][r] = xp[g][r];

        for (int k4 = 0; k4 < 64; ++k4) {
            float4 a0 = w0[k4], a1 = w1[k4], a2 = w2[k4], a3 = w3[k4];
            #pragma unroll
            for (int r = 0; r < 8; ++r) {
                float4 hv = *(const float4*)&buf[(rbase + r) * 256 + k4 * 4];
                ga[0][r] = fmaf(hv.w, a0.w, fmaf(hv.z, a0.z, fmaf(hv.y, a0.y, fmaf(hv.x, a0.x, ga[0][r]))));
                ga[1][r] = fmaf(hv.w, a1.w, fmaf(hv.z, a1.z, fmaf(hv.y, a1.y, fmaf(hv.x, a1.x, ga[1][r]))));
                ga[2][r] = fmaf(hv.w, a2.w, fmaf(hv.z, a2.z, fmaf(hv.y, a2.y, fmaf(hv.x, a2.x, ga[2][r]))));
                ga[3][r] = fmaf(hv.w, a3.w, fmaf(hv.z, a3.z, fmaf(hv.y, a3.y, fmaf(hv.x, a3.x, ga[3][r]))));
            }
        }

        float hs = 0.0f;
        #pragma unroll
        for (int r = 0; r < 8; ++r) {
            float iv = sigmoidf_(ga[0][r]);
            float fv = sigmoidf_(ga[1][r]);
            float gv = tanhf(ga[2][r]);
            float ov = sigmoidf_(ga[3][r]);
            c[r] = fv * c[r] + iv * gv;
            h[r] = ov * tanhf(c[r]);
            hs += h[r];
        }
        atomicAdd(&esum[t * GH + j], hs);
        __syncthreads();   // all reads of buf done before next-step overwrite
    }
}

// ---------------------------------------------------------------------------
// Kernel C: proj[t][c] = (esum[t]/4096) @ W1_h + att_b1[c]
// Grid: 32 blocks x 64 threads.
// ---------------------------------------------------------------------------
__global__ void proj_kernel(const float* __restrict__ esum,
                            const float* __restrict__ attW1,
                            const float* __restrict__ attb1,
                            float* __restrict__ proj)
{
    int t = blockIdx.x, cix = threadIdx.x;
    float a = attb1[cix];
    for (int k = 0; k < GH; ++k) {
        float e = esum[t * GH + k] * (1.0f / (float)N_TRAIN);
        a = fmaf(e, attW1[(N_TRAIN + k) * AH + cix], a);
    }
    proj[t * AH + cix] = a;
}

// ---------------------------------------------------------------------------
// Kernel D: S_proj (registers) fused with per-step scores.
// Grid: 512 blocks x 256 threads. Block owns 64 antes; thread (a = tid&63,
// ch = tid>>6) accumulates cols [ch*16, ch*16+16).
// scores[t][a] = sum_c relu(S_proj[a][c] + proj[t][c]) * w2[c] + b2
// ---------------------------------------------------------------------------
__global__ __launch_bounds__(256, 2) void scores_kernel(
    const float* __restrict__ S,
    const float* __restrict__ attW1,
    const float* __restrict__ proj,
    const float* __restrict__ attw2,
    const float* __restrict__ attb2,
    float* __restrict__ out)
{
    __shared__ float wl[64 * AH];        // 16 KB: 64-row chunk of att_W1
    __shared__ float projl[TSTEPS * AH]; // 8 KB
    __shared__ float w2l[AH];
    __shared__ float part[256];

    const int tid = threadIdx.x;
    const int a0  = blockIdx.x * 64;
    const int ai  = tid & 63;
    const int ch  = tid >> 6;            // 0..3, cols ch*16..+16
    const int a   = a0 + ai;

    float sp[16];
    #pragma unroll
    for (int q = 0; q < 16; ++q) sp[q] = 0.0f;

    for (int chunk = 0; chunk < N_TRAIN / 64; ++chunk) {
        __syncthreads();
        for (int t = tid; t < 64 * AH; t += 256)
            wl[t] = attW1[chunk * 64 * AH + t];
        __syncthreads();
        #pragma unroll 4
        for (int rr = 0; rr < 64; ++rr) {
            float s = S[(size_t)(chunk * 64 + rr) * NANTES + a];
            const float* w = &wl[rr * AH + ch * 16];
            #pragma unroll
            for (int q = 0; q < 16; ++q)
                sp[q] = fmaf(s, w[q], sp[q]);
        }
    }

    for (int t = tid; t < TSTEPS * AH; t += 256) projl[t] = proj[t];
    if (tid < AH) w2l[tid] = attw2[tid];
    __syncthreads();

    const float b2v = attb2[0];
    for (int t = 0; t < TSTEPS; ++t) {
        float s = 0.0f;
        const float* pr  = &projl[t * AH + ch * 16];
        const float* w2p = &w2l[ch * 16];
        #pragma unroll
        for (int q = 0; q < 16; ++q)
            s += fmaxf(sp[q] + pr[q], 0.0f) * w2p[q];
        part[tid] = s;
        __syncthreads();
        if (tid < 64)
            out[(size_t)t * NANTES + a0 + tid] =
                part[tid] + part[tid + 64] + part[tid + 128] + part[tid + 192] + b2v;
        __syncthreads();
    }
}

// ---------------------------------------------------------------------------
// Kernel E: per-step argmax over 32768 antes (first-max semantics).
// Grid: 32 blocks x 256 threads.
// ---------------------------------------------------------------------------
__global__ void argmax_kernel(const float* __restrict__ scores,
                              float* __restrict__ out)
{
    __shared__ float bv[256];
    __shared__ int   bidx[256];
    const int t = blockIdx.x, tid = threadIdx.x;
    float best = -INFINITY;
    int   bi   = 0x7fffffff;
    for (int a = tid; a < NANTES; a += 256) {
        float v = scores[(size_t)t * NANTES + a];
        if (v > best) { best = v; bi = a; }   // a increasing -> first max per thread
    }
    bv[tid] = best; bidx[tid] = bi;
    __syncthreads();
    for (int s = 128; s > 0; s >>= 1) {
        if (tid < s) {
            if (bv[tid + s] > bv[tid] ||
                (bv[tid + s] == bv[tid] && bidx[tid + s] < bidx[tid])) {
                bv[tid] = bv[tid + s];
                bidx[tid] = bidx[tid + s];
            }
        }
        __syncthreads();
    }
    if (tid == 0)
        out[(size_t)TSTEPS * NANTES + t] = (float)bidx[0];
}

// ---------------------------------------------------------------------------
extern "C" void kernel_launch(void* const* d_in, const int* in_sizes, int n_in,
                              void* d_out, int out_size, void* d_ws, size_t ws_size,
                              hipStream_t stream)
{
    const float* ctx   = (const float*)d_in[0];
    const float* S     = (const float*)d_in[1];
    const float* encW1 = (const float*)d_in[2];
    const float* encb1 = (const float*)d_in[3];
    const float* encW2 = (const float*)d_in[4];
    const float* encb2 = (const float*)d_in[5];
    const float* Wih   = (const float*)d_in[6];
    const float* Whh   = (const float*)d_in[7];
    const float* bih   = (const float*)d_in[8];
    const float* bhh   = (const float*)d_in[9];
    const float* attW1 = (const float*)d_in[10];
    const float* attb1 = (const float*)d_in[11];
    const float* attw2 = (const float*)d_in[12];
    const float* attb2 = (const float*)d_in[13];

    float* esum = (float*)d_ws;                  // 32*256 floats = 32 KB
    float* proj = esum + TSTEPS * GH;            // 32*64 floats  = 8 KB
    float* out  = (float*)d_out;

    zero_kernel<<<dim3(8), dim3(256), 0, stream>>>(esum);
    lstm_kernel<<<dim3(N_TRAIN / 16), dim3(512), 0, stream>>>(
        ctx, encW1, encb1, encW2, encb2, Wih, Whh, bih, bhh, esum);
    proj_kernel<<<dim3(TSTEPS), dim3(AH), 0, stream>>>(esum, attW1, attb1, proj);
    scores_kernel<<<dim3(NANTES / 64), dim3(256), 0, stream>>>(
        S, attW1, proj, attw2, attb2, out);
    argmax_kernel<<<dim3(TSTEPS), dim3(256), 0, stream>>>(out, out);
}